// Round 6
// baseline (1318.812 us; speedup 1.0000x reference)
//
#include <hip/hip_runtime.h>

// Problem constants
constexpr int D  = 128;
constexpr int M  = 8192;
constexpr int L  = 5;
constexpr int K  = 8;
constexpr int KL = 4;
constexpr int G  = 4096;

constexpr int TB   = 64;            // bucket pad granularity == row tile
constexpr int PADL = M + K * TB;    // 8704 -> 136 row-tiles of 64
constexpr int PADG = G + KL * TB;   // 4352 -> 68 row-tiles of 64

typedef short bf16x8 __attribute__((ext_vector_type(8)));
typedef float f32x4  __attribute__((ext_vector_type(4)));

__device__ __forceinline__ unsigned short f2bf(float x) {
  union { float f; unsigned int u; } c; c.f = x;
  unsigned int u = c.u + 0x7FFF + ((c.u >> 16) & 1);   // RNE
  return (unsigned short)(u >> 16);
}
__device__ __forceinline__ float bf2f(unsigned short h) {
  union { unsigned int u; float f; } c; c.u = ((unsigned int)h) << 16;
  return c.f;
}

// ---------------------------------------------------------------------------
__global__ void leaf_gather_kernel(const int* __restrict__ leaf_ids,
                                   const float* __restrict__ emb,
                                   float* __restrict__ h0) {
  int idx = blockIdx.x * 256 + threadIdx.x;
  int n = idx >> 7, d = idx & 127;
  h0[idx] = emb[(size_t)leaf_ids[n] * D + d];
}

// out = o0 + o1 (final split-K reduction for logic layer 2)
__global__ void add_out_kernel(const float* __restrict__ o0,
                               const float* __restrict__ o1,
                               float* __restrict__ out) {
  int idx = blockIdx.x * 256 + threadIdx.x;
  out[idx] = o0[idx] + o1[idx];
}

// ---------------------------------------------------------------------------
// Bucket node indices by fid, padded to 64; pad = -1. Valid entries are a
// prefix of each bucket, so every 64-row tile is fid-uniform.
__global__ void bucket64_kernel(const int* __restrict__ nf_fid,
                                const int* __restrict__ lf_fid,
                                int* __restrict__ orders) {
  int b = blockIdx.x;
  const int* fid; int N, Kf, cap; int* out;
  if (b < L) { fid = nf_fid + b * M; N = M; Kf = K;  cap = PADL; out = orders + b * PADL; }
  else       { fid = lf_fid;         N = G; Kf = KL; cap = PADG; out = orders + L * PADL; }
  __shared__ int cnt[8];
  __shared__ int cur[8];
  int tid = threadIdx.x;
  if (tid < Kf) cnt[tid] = 0;
  __syncthreads();
  for (int i = tid; i < N; i += 256) atomicAdd(&cnt[fid[i]], 1);
  __syncthreads();
  if (tid == 0) {
    int off = 0;
    for (int k = 0; k < Kf; ++k) { cur[k] = off; off += ((cnt[k] + TB - 1) / TB) * TB; }
  }
  __syncthreads();
  for (int i = tid; i < cap; i += 256) out[i] = -1;
  __syncthreads();
  for (int i = tid; i < N; i += 256) {
    int kk = fid[i];
    int pos = atomicAdd(&cur[kk], 1);
    out[pos] = i;
  }
}

// ---------------------------------------------------------------------------
// Weight prep: W[k][KD][F] fp32 -> BT[k][F][2*KD] bf16 as [hi(KD) | lo(KD)].
__global__ void prep_kernel(const float* __restrict__ W1, const float* __restrict__ W2,
                            const float* __restrict__ W3, const float* __restrict__ Wl1,
                            const float* __restrict__ Wl2,
                            short* __restrict__ B1T, short* __restrict__ B2T,
                            short* __restrict__ B3T, short* __restrict__ BL1T,
                            short* __restrict__ BL2T) {
  int b = blockIdx.x;
  const float* W; short* BT; int KD, F;
  if      (b < 4096) { W = W1;  BT = B1T;  KD = 256; F = 512; }
  else if (b < 6144) { W = W2;  BT = B2T;  KD = 512; F = 256; b -= 4096; }
  else if (b < 7168) { W = W3;  BT = B3T;  KD = 256; F = 128; b -= 6144; }
  else if (b < 9216) { W = Wl1; BT = BL1T; KD = 256; F = 512; b -= 7168; }
  else               { W = Wl2; BT = BL2T; KD = 512; F = 128; b -= 9216; }
  int k = b / F, f = b % F;
  for (int d = threadIdx.x; d < KD; d += 256) {
    float w = W[((size_t)k * KD + d) * F + f];
    unsigned short hi = f2bf(w);
    unsigned short lo = f2bf(w - bf2f(hi));
    BT[((size_t)k * F + f) * (2 * KD) + d]      = (short)hi;
    BT[((size_t)k * F + f) * (2 * KD) + KD + d] = (short)lo;
  }
}

// ---------------------------------------------------------------------------
// Gather + split: xs[r][0:256]=hi(concat(h[gl],h[gr])), xs[r][256:512]=lo.
// SUMIN=1: input h is a split-K partial pair h0,h1 (summed here).
// Padded rows (order=-1) are zero-filled. 32 rows/block, 8 thr/row.
template<int SUMIN>
__global__ __launch_bounds__(256) void gather_split_kernel(
    const float* __restrict__ h0, const float* __restrict__ h1,
    const int* __restrict__ order,
    const int* __restrict__ gl, const int* __restrict__ gr,
    short* __restrict__ xs) {
  const int r = blockIdx.x * 32 + (threadIdx.x >> 3);
  const int d0 = (threadIdx.x & 7) * 32;
  const int node = order[r];
  float v[32];
  if (node >= 0) {
    const int src = (d0 < 128) ? gl[node] : gr[node];
    const int dd = (d0 < 128) ? d0 : d0 - 128;
    const float4* p0 = (const float4*)(h0 + (size_t)src * 128 + dd);
    #pragma unroll
    for (int i = 0; i < 8; ++i) ((float4*)v)[i] = p0[i];
    if (SUMIN) {
      const float4* p1 = (const float4*)(h1 + (size_t)src * 128 + dd);
      #pragma unroll
      for (int i = 0; i < 8; ++i) {
        float4 w = p1[i];
        v[4 * i + 0] += w.x; v[4 * i + 1] += w.y;
        v[4 * i + 2] += w.z; v[4 * i + 3] += w.w;
      }
    }
  } else {
    #pragma unroll
    for (int i = 0; i < 32; ++i) v[i] = 0.f;
  }
  union { unsigned short u[32]; int4 q[4]; } hi, lo;
  #pragma unroll
  for (int i = 0; i < 32; ++i) {
    unsigned short hh = f2bf(v[i]);
    hi.u[i] = hh;
    lo.u[i] = f2bf(v[i] - bf2f(hh));
  }
  int4* dh = (int4*)&xs[(size_t)r * 512 + d0];
  int4* dl = (int4*)&xs[(size_t)r * 512 + 256 + d0];
  #pragma unroll
  for (int i = 0; i < 4; ++i) { dh[i] = hi.q[i]; dl[i] = lo.q[i]; }
}

// ---------------------------------------------------------------------------
// Grouped GEMM, split-bf16 (logical K' = 3*KH over phys layout [hi|lo]):
//   A' segs {0,1,2} -> phys {hi, lo, hi};  B' segs -> {hi, hi, lo}
// Block: 256 thr, 64 rows x TC cols; BK=128 (few barriers, m97-style LDS
// single-buffer, depth-2 register prefetch). Waves 2x2; wave tile 32 x TC/2.
// NZ>1: blockIdx.z selects a K'-slice (split-K, EPI==1 only); consumer sums.
// EPI=0: relu(acc+bias) -> split hi/lo bf16 to Aout (coalesced via LDS).
// EPI=1: acc (+bias iff z==0) -> fp32 scatter to outp + z*partStride.
template<int KH, int NN, int TC, int EPI, int NZ>
__global__ __launch_bounds__(256) void mfma_gemm(
    const short* __restrict__ A, const short* __restrict__ BT,
    const float* __restrict__ bias,
    short* __restrict__ Aout, float* __restrict__ outp, size_t partStride,
    const int* __restrict__ order, const int* __restrict__ fid) {
  constexpr int BK  = 128;
  constexpr int NCH = 3 * KH / BK;          // 6 (KH=256) or 12 (KH=512)
  static_assert(NCH % NZ == 0, "split must divide chunks");
  constexpr int CN  = NCH / NZ;
  constexpr int LDA = BK + 8;               // 136 shorts; 68-dword stride -> 2-way
  constexpr int CF  = TC / 32;              // col frags per wave (2 or 4)
  constexpr int SPB = TC * BK / 256;        // B staging shorts/thread (32 or 64)
  constexpr int TPB = BK / SPB;             // B staging threads/col (4 or 2)
  __shared__ __align__(16) short As[64 * LDA];
  __shared__ __align__(16) short Bs[TC * LDA];
  __shared__ int nodesS[64];

  const int tid = threadIdx.x;
  const int row0 = blockIdx.x * 64;
  const int ct = blockIdx.y;
  const int z  = blockIdx.z;

  if (tid < 64) nodesS[tid] = order[row0 + tid];
  __syncthreads();
  if (nodesS[0] < 0) return;                // fully-padded tile
  const int kfn = fid[nodesS[0]];
  const short* __restrict__ Bk = BT + (size_t)kfn * NN * (2 * KH);

  const int lane = tid & 63, wave = tid >> 6;
  const int l15 = lane & 15, oct = lane >> 4;
  const int wr  = (wave >> 1) * 32;         // wave row base
  const int wcg = (wave & 1) * (TC / 2);    // wave col base

  const int ar = tid >> 2;                  // A staging: 64 rows x 4 thr
  const int ag = (tid & 3) * 32;            // 32 shorts (4 int4)
  const int bcol = tid / TPB;               // B staging col
  const int bg = (tid % TPB) * SPB;         // 32 or 64 shorts

  const int c0 = z * CN;

  f32x4 acc[2][CF];
  #pragma unroll
  for (int i = 0; i < 2; ++i)
    #pragma unroll
    for (int j = 0; j < CF; ++j) acc[i][j] = (f32x4)0.f;

  int4 Areg[2][4];
  int4 Breg[2][SPB / 8];

  auto loadA = [&](int set, int c) {
    int ko = c * BK, seg = ko / KH, wi = ko % KH;
    int pa = (seg == 1) ? KH + wi : wi;
    const int4* p = (const int4*)(A + (size_t)(row0 + ar) * (2 * KH) + pa + ag);
    #pragma unroll
    for (int q = 0; q < 4; ++q) Areg[set][q] = p[q];
  };
  auto loadB = [&](int set, int c) {
    int ko = c * BK, seg = ko / KH, wi = ko % KH;
    int pb = (seg == 2) ? KH + wi : wi;
    const int4* p = (const int4*)(Bk + (size_t)(ct * TC + bcol) * (2 * KH) + pb + bg);
    #pragma unroll
    for (int q = 0; q < SPB / 8; ++q) Breg[set][q] = p[q];
  };
  auto storeLDS = [&](int set) {
    int4* da = (int4*)&As[ar * LDA + ag];
    #pragma unroll
    for (int q = 0; q < 4; ++q) da[q] = Areg[set][q];
    int4* db = (int4*)&Bs[bcol * LDA + bg];
    #pragma unroll
    for (int q = 0; q < SPB / 8; ++q) db[q] = Breg[set][q];
  };
  auto compute = [&]() {
    #pragma unroll
    for (int ss = 0; ss < BK / 32; ++ss) {
      const int ko = ss * 32 + oct * 8;
      bf16x8 a0 = *(const bf16x8*)&As[(wr + l15) * LDA + ko];
      bf16x8 a1 = *(const bf16x8*)&As[(wr + 16 + l15) * LDA + ko];
      #pragma unroll
      for (int cf = 0; cf < CF; ++cf) {
        bf16x8 b = *(const bf16x8*)&Bs[(wcg + cf * 16 + l15) * LDA + ko];
        acc[0][cf] = __builtin_amdgcn_mfma_f32_16x16x32_bf16(a0, b, acc[0][cf], 0, 0, 0);
        acc[1][cf] = __builtin_amdgcn_mfma_f32_16x16x32_bf16(a1, b, acc[1][cf], 0, 0, 0);
      }
    }
  };

  loadA(0, c0); loadB(0, c0);
  if (CN > 1) { loadA(1, c0 + 1); loadB(1, c0 + 1); }
  for (int c = 0; c < CN; ++c) {
    const int s = c & 1;
    __syncthreads();
    storeLDS(s);
    __syncthreads();
    if (c + 2 < CN) { loadA(s, c0 + c + 2); loadB(s, c0 + c + 2); }
    compute();
  }

  // ---- Epilogue (coalesced via LDS reuse of Bs; barrier-guarded)
  // C/D layout: col = l15, row = oct*4 + j (m89-verified).
  if (EPI == 0) {
    short* Ls = (short*)Bs;                 // 64 x TC shorts <= Bs capacity
    #pragma unroll
    for (int part = 0; part < 2; ++part) {
      __syncthreads();
      #pragma unroll
      for (int rf = 0; rf < 2; ++rf)
        #pragma unroll
        for (int cf = 0; cf < CF; ++cf) {
          int colL = wcg + cf * 16 + l15;
          float bv = bias[kfn * NN + ct * TC + colL];
          #pragma unroll
          for (int j = 0; j < 4; ++j) {
            int row = wr + rf * 16 + oct * 4 + j;
            float v = fmaxf(acc[rf][cf][j] + bv, 0.f);
            unsigned short hh = f2bf(v);
            unsigned short val = (part == 0) ? hh : f2bf(v - bf2f(hh));
            Ls[row * TC + colL] = (short)val;
          }
        }
      __syncthreads();
      constexpr int SPT = TC / 4;           // shorts per thread (16 or 32)
      int row = tid >> 2, sg = (tid & 3) * SPT;
      const int4* src = (const int4*)&Ls[row * TC + sg];
      int4* dst = (int4*)&Aout[(size_t)(row0 + row) * (2 * NN) + part * NN + ct * TC + sg];
      #pragma unroll
      for (int q = 0; q < SPT / 8; ++q) dst[q] = src[q];
    }
  } else {
    float* Lf = (float*)Bs;                 // 64 x TC floats = TC*256 B <= TC*272 B
    __syncthreads();
    #pragma unroll
    for (int rf = 0; rf < 2; ++rf)
      #pragma unroll
      for (int cf = 0; cf < CF; ++cf) {
        int colL = wcg + cf * 16 + l15;
        float bv = (z == 0) ? bias[kfn * NN + ct * TC + colL] : 0.f;
        #pragma unroll
        for (int j = 0; j < 4; ++j) {
          int row = wr + rf * 16 + oct * 4 + j;
          Lf[row * TC + colL] = acc[rf][cf][j] + bv;
        }
      }
    __syncthreads();
    float* outz = outp + (size_t)z * partStride;
    constexpr int FPT = TC / 4;             // floats per thread (16 or 32)
    int row = tid >> 2, fo = (tid & 3) * FPT;
    int node = nodesS[row];
    if (node >= 0) {
      const float4* src = (const float4*)&Lf[row * TC + fo];
      float4* dst = (float4*)&outz[(size_t)node * NN + ct * TC + fo];
      #pragma unroll
      for (int q = 0; q < FPT / 4; ++q) dst[q] = src[q];
    }
  }
}

// ---------------------------------------------------------------------------
extern "C" void kernel_launch(void* const* d_in, const int* in_sizes, int n_in,
                              void* d_out, int out_size, void* d_ws, size_t ws_size,
                              hipStream_t stream) {
  const int*   leaf_ids  = (const int*)d_in[0];
  const int*   left_idx  = (const int*)d_in[1];
  const int*   right_idx = (const int*)d_in[2];
  const int*   nf_fid    = (const int*)d_in[3];
  const int*   gt_left   = (const int*)d_in[4];
  const int*   gt_right  = (const int*)d_in[5];
  const int*   lf_fid    = (const int*)d_in[6];
  const float* emb       = (const float*)d_in[7];
  const float* W1 = (const float*)d_in[8];
  const float* b1 = (const float*)d_in[9];
  const float* W2 = (const float*)d_in[10];
  const float* b2 = (const float*)d_in[11];
  const float* W3 = (const float*)d_in[12];
  const float* b3 = (const float*)d_in[13];
  const float* Wl1 = (const float*)d_in[14];
  const float* bl1 = (const float*)d_in[15];
  const float* Wl2 = (const float*)d_in[16];
  const float* bl2 = (const float*)d_in[17];
  float* out = (float*)d_out;

  const size_t SZ_H    = (size_t)M * D * 4;            // 4 MiB
  const size_t SZ_O    = (size_t)G * D * 4;            // 2 MiB
  const size_t SZ_XS   = (size_t)PADL * 512 * 2;       // 8.9 MB
  const size_t SZ_A1   = (size_t)PADL * 1024 * 2;      // 17.8 MB
  const size_t SZ_A2   = (size_t)PADL * 512 * 2;       // 8.9 MB
  const size_t SZ_B1T  = (size_t)8 * 512 * 512 * 2;
  const size_t SZ_B2T  = (size_t)8 * 256 * 1024 * 2;
  const size_t SZ_B3T  = (size_t)8 * 128 * 512 * 2;
  const size_t SZ_BL1T = (size_t)4 * 512 * 512 * 2;
  const size_t SZ_BL2T = (size_t)4 * 128 * 1024 * 2;

  char* p = (char*)d_ws;
  float* hA  = (float*)p;  p += SZ_H;
  float* p0  = (float*)p;  p += SZ_H;   // partial pair A (contiguous!)
  float* p1  = (float*)p;  p += SZ_H;
  float* q0  = (float*)p;  p += SZ_H;   // partial pair B (contiguous!)
  float* q1  = (float*)p;  p += SZ_H;
  float* o0  = (float*)p;  p += SZ_O;   // logic2 partials (contiguous!)
  float* o1  = (float*)p;  p += SZ_O;
  short* xsb = (short*)p;  p += SZ_XS;
  short* a1s = (short*)p;  p += SZ_A1;
  short* a2s = (short*)p;  p += SZ_A2;
  short* B1T  = (short*)p; p += SZ_B1T;
  short* B2T  = (short*)p; p += SZ_B2T;
  short* B3T  = (short*)p; p += SZ_B3T;
  short* BL1T = (short*)p; p += SZ_BL1T;
  short* BL2T = (short*)p; p += SZ_BL2T;
  int*   orders = (int*)p;

  leaf_gather_kernel<<<(M * D) / 256, 256, 0, stream>>>(leaf_ids, emb, hA);
  bucket64_kernel<<<L + 1, 256, 0, stream>>>(nf_fid, lf_fid, orders);
  prep_kernel<<<9728, 256, 0, stream>>>(W1, W2, W3, Wl1, Wl2,
                                        B1T, B2T, B3T, BL1T, BL2T);

  const size_t HSTRIDE = (size_t)M * D;
  float* in0 = hA; float* in1 = nullptr;
  float* ou0 = q0;
  for (int l = 0; l < L; ++l) {
    const int* ord = orders + l * PADL;
    const int* fidl = nf_fid + l * M;
    if (l == 0) {
      gather_split_kernel<0><<<PADL / 32, 256, 0, stream>>>(
          in0, nullptr, ord, left_idx, right_idx, xsb);
    } else {
      gather_split_kernel<1><<<PADL / 32, 256, 0, stream>>>(
          in0, in1, ord, left_idx + l * M, right_idx + l * M, xsb);
    }
    // GEMM1: K'=768, N=512, TC=128 -> (136,4) = 544 blocks
    mfma_gemm<256, 512, 128, 0, 1><<<dim3(PADL / 64, 4, 1), 256, 0, stream>>>(
        xsb, B1T, b1, a1s, nullptr, 0, ord, fidl);
    // GEMM2: K'=1536, N=256, TC=64 -> (136,4) = 544 blocks
    mfma_gemm<512, 256, 64, 0, 1><<<dim3(PADL / 64, 4, 1), 256, 0, stream>>>(
        a1s, B2T, b2, a2s, nullptr, 0, ord, fidl);
    // GEMM3: K'=768, N=128, TC=64, split-K 2 -> (136,2,2) = 544 blocks
    mfma_gemm<256, 128, 64, 1, 2><<<dim3(PADL / 64, 2, 2), 256, 0, stream>>>(
        a2s, B3T, b3, nullptr, ou0, HSTRIDE, ord, fidl);
    in0 = ou0; in1 = ou0 + HSTRIDE;
    ou0 = (ou0 == q0) ? p0 : q0;
  }
  const int* ordG = orders + L * PADL;
  gather_split_kernel<1><<<PADG / 32, 256, 0, stream>>>(
      in0, in1, ordG, gt_left, gt_right, xsb);
  // Logic GEMM1: K'=768, N=512, TC=64 -> (68,8) = 544 blocks
  mfma_gemm<256, 512, 64, 0, 1><<<dim3(PADG / 64, 8, 1), 256, 0, stream>>>(
      xsb, BL1T, bl1, a1s, nullptr, 0, ordG, lf_fid);
  // Logic GEMM2: K'=1536, N=128, TC=64, split-K 2 -> (68,2,2) = 272 blocks
  mfma_gemm<512, 128, 64, 1, 2><<<dim3(PADG / 64, 2, 2), 256, 0, stream>>>(
      a1s, BL2T, bl2, nullptr, o0, (size_t)G * D, ordG, lf_fid);
  add_out_kernel<<<(G * D) / 256, 256, 0, stream>>>(o0, o1, out);
}